// Round 7
// baseline (49.373 us; speedup 1.0000x reference)
//
#include <hip/hip_runtime.h>
#include <math.h>

#define HH 384
#define WW 512
#define RR 60
#define KLEN 121             // 2*RR+1
#define TH 32                // rows per tile in k_main
#define NT2 (HH / TH)        // 12 tiles per image
#define NBUK 24              // 16-row buckets per image (CSR granularity)
#define BATCH 128            // harness batch (out_size)
#define MAXF 400             // per-image fixation capacity (mean ~100)
#define SALB 192             // saliency partial blocks: 192*256 float4 = HH*WW

typedef float v2f __attribute__((ext_vector_type(2)));

// ---- kernel 1: blocks [0,batch) = per-image bucket sort + mass;
//                blocks [batch, batch+SALB) = saliency partial sums ----------
__global__ __launch_bounds__(256) void k_prep(
    const float* __restrict__ sal, const int* __restrict__ ns,
    const int* __restrict__ ys, const int* __restrict__ xs,
    float* __restrict__ kk_g, float* __restrict__ partial,
    float* __restrict__ ssum_g, int* __restrict__ offs_g,
    int* __restrict__ sorted, float* __restrict__ out,
    int nfix, int batch)
{
    const int tid = threadIdx.x;

    if (blockIdx.x >= batch) {
        // ---- saliency partial: 256 float4 per block, one plain store -------
        __shared__ float redp[4];
        const int sb = blockIdx.x - batch;
        float4 v = ((const float4*)sal)[sb * 256 + tid];
        float a = (v.x + v.y) + (v.z + v.w);
        for (int o = 32; o > 0; o >>= 1) a += __shfl_down(a, o, 64);
        if ((tid & 63) == 0) redp[tid >> 6] = a;
        __syncthreads();
        if (tid == 0) partial[sb] = redp[0] + redp[1] + redp[2] + redp[3];
        return;
    }

    // ---- per-image block ----
    __shared__ float kk_s[KLEN];
    __shared__ float P_s[KLEN + 1];
    __shared__ int   list[MAXF];
    __shared__ int   cntb[NBUK];
    __shared__ int   off_s[NBUK + 1];
    __shared__ int   cur[NBUK];
    __shared__ int   nloc;
    __shared__ float red2[4];

    const int n = blockIdx.x;

    if (tid < KLEN) {
        float xx = (float)(tid - RR) * (1.0f / 20.0f);
        kk_s[tid] = expf(-0.5f * xx * xx);
    }
    if (tid < NBUK) { cntb[tid] = 0; cur[tid] = 0; }
    if (tid == 0) nloc = 0;
    __syncthreads();
    if (tid == 0) {                    // normalize + prefix (242 float ops)
        float s = 0.f;
        for (int t = 0; t < KLEN; ++t) s += kk_s[t];
        float inv = 1.0f / s, run = 0.f;
        for (int t = 0; t < KLEN; ++t) {
            float v = kk_s[t] * inv;
            kk_s[t] = v; P_s[t] = run; run += v;
        }
        P_s[KLEN] = run;
    }
    __syncthreads();

    // scan all fixations (ns is L2-resident), collect this image's
    float ss = 0.f;
    const int4* ns4 = (const int4*)ns;
    const int nf4 = nfix >> 2;
    for (int i = tid; i < nf4; i += 256) {
        int4 n4 = ns4[i];
        #pragma unroll
        for (int e = 0; e < 4; ++e) {
            if ((&n4.x)[e] == n) {
                const int idx = 4 * i + e;
                const int y = ys[idx], x = xs[idx];
                const int pos = atomicAdd(&nloc, 1);
                if (pos < MAXF) list[pos] = (y << 9) | x;
                atomicAdd(&cntb[y >> 4], 1);
                float cy = P_s[RR + min(RR, HH - 1 - y) + 1] - P_s[RR - min(RR, y)];
                float cx = P_s[RR + min(RR, WW - 1 - x) + 1] - P_s[RR - min(RR, x)];
                ss += cy * cx;
            }
        }
    }
    for (int idx = (nf4 << 2) + tid; idx < nfix; idx += 256) {
        if (ns[idx] == n) {
            const int y = ys[idx], x = xs[idx];
            const int pos = atomicAdd(&nloc, 1);
            if (pos < MAXF) list[pos] = (y << 9) | x;
            atomicAdd(&cntb[y >> 4], 1);
            float cy = P_s[RR + min(RR, HH - 1 - y) + 1] - P_s[RR - min(RR, y)];
            float cx = P_s[RR + min(RR, WW - 1 - x) + 1] - P_s[RR - min(RR, x)];
            ss += cy * cx;
        }
    }
    for (int o = 32; o > 0; o >>= 1) ss += __shfl_down(ss, o, 64);
    if ((tid & 63) == 0) red2[tid >> 6] = ss;
    __syncthreads();                   // atomics + red2 done
    if (tid == 0) {
        ssum_g[n] = red2[0] + red2[1] + red2[2] + red2[3];
        int run = 0;                   // exclusive scan over 24 buckets
        for (int t = 0; t < NBUK; ++t) { off_s[t] = run; run += cntb[t]; }
        off_s[NBUK] = run;
    }
    __syncthreads();
    const int m = min(nloc, MAXF);
    for (int j = tid; j < m; j += 256) {
        const int p = list[j];
        const int key = (p >> 9) >> 4;
        const int pos = atomicAdd(&cur[key], 1);
        sorted[n * MAXF + off_s[key] + pos] = p;
    }
    if (tid <= NBUK) offs_g[n * 32 + tid] = n * MAXF + off_s[tid];
    if (n == 0 && tid < KLEN) kk_g[tid] = kk_s[tid];
    if (tid == 0) out[n] = 0.f;
}

// ---------------- main: register-accumulator Gaussian splat, fused min-sum ----
// 32-row tiles (12 blocks/image): halves per-(fixation,block) fixed costs and
// prologue/epilogue count vs 16-row tiles. Thread t owns adjacent columns
// 2t,2t+1; rows packed as float2 pairs -> ds_read_b64 + v_pk_fma_f32 inner loop.
__global__ __launch_bounds__(256) void k_main(
    const float* __restrict__ sal, const int* __restrict__ offs,
    const int* __restrict__ sorted, const float* __restrict__ ssum,
    const float* __restrict__ partial, const float* __restrict__ kk_g,
    float* __restrict__ out)
{
    // padded row-weight table: kpy[v] = kk[v-91] for v in [91,211], else 0
    // (v = (r0+i) - y + 151 - 60 ... i.e. access kpy[i + B], B = r0-y+151-60+?)
    // Concretely: weight(row i) = kk[(r0+i)-y+60]; with B = r0-y+151, index
    // i+B-91 into kk => kpy[i+B] where kpy[v]=kk[v-91] (0 outside).
    __shared__ v2f   kpE[122];   // pairs starting at even kpy index
    __shared__ v2f   kpO[122];   // pairs starting at odd kpy index
    __shared__ float kkx[128];   // x-kernel: [0..120] = kk, [121..127] = 0
    __shared__ int   fix_s[256];
    __shared__ float part[4];
    __shared__ float redp[4];

    const int n   = blockIdx.y;
    const int t   = blockIdx.x;
    const int r0  = t * TH;
    const int tid = threadIdx.x;

    if (tid < 122) {
        const int u = 2 * tid;
        const float e0 = ((unsigned)(u - 91)     <= 120u) ? kk_g[u - 91]     : 0.f;
        const float e1 = ((unsigned)(u - 91 + 1) <= 120u) ? kk_g[u - 91 + 1] : 0.f;
        const float e2 = ((unsigned)(u - 91 + 2) <= 120u) ? kk_g[u - 91 + 2] : 0.f;
        kpE[tid] = (v2f){e0, e1};
        kpO[tid] = (v2f){e1, e2};
    }
    if (tid < 128) kkx[tid] = (tid < KLEN) ? kk_g[tid] : 0.f;
    float psal = (tid < SALB) ? partial[tid] : 0.f;   // issue early

    v2f a0[16], a1[16];
    #pragma unroll
    for (int i = 0; i < 16; ++i) { a0[i] = 0.f; a1[i] = 0.f; }

    const int b0 = max(0, 2 * t - 4);
    const int b1 = min(NBUK - 1, 2 * t + 5);
    const int s0 = offs[n * 32 + b0], s1 = offs[n * 32 + b1 + 1];

    const int c0  = 2 * tid;
    const int wlo = (tid >> 6) << 7;      // wave's column strip [wlo, wlo+127]
    const int whi = wlo + 127;

    for (int fb = s0; fb < s1; fb += 256) {
        const int m = min(256, s1 - fb);
        if (fb != s0) __syncthreads();            // protect fix_s overwrite
        if (tid < m) fix_s[tid] = sorted[fb + tid];
        __syncthreads();                          // also covers kpE/kpO/kkx once
        for (int f = 0; f < m; ++f) {
            const int p = fix_s[f];               // broadcast LDS read
            const int y = p >> 9, x = p & 511;
            const int B = r0 - y + 151;           // row-weight base in kpy
            if ((unsigned)B > 211u) continue;     // uniform: y out of range
            if (x + RR < wlo || x - RR > whi) continue;   // wave-uniform: x skip
            const int idx0 = c0 - x + RR;
            const float wx0 = kkx[min((unsigned)idx0, 127u)];
            const float wx1 = kkx[min((unsigned)(idx0 + 1), 127u)];
            const v2f* kp = (B & 1) ? kpO : kpE;
            const int kb = B >> 1;
            #pragma unroll
            for (int i = 0; i < 16; ++i) {
                const v2f wy = kp[kb + i];        // rows 2i,2i+1 (b64 broadcast)
                a0[i] += wy * wx0;                // v_pk_fma_f32
                a1[i] += wy * wx1;
            }
        }
    }

    // reduce saliency partials -> invSal
    for (int o = 32; o > 0; o >>= 1) psal += __shfl_down(psal, o, 64);
    if ((tid & 63) == 0) redp[tid >> 6] = psal;
    __syncthreads();
    const float invSal = 1.0f / (redp[0] + redp[1] + redp[2] + redp[3]);

    const float sN    = ssum[n];
    const float invSn = sN > 0.f ? 1.0f / sN : 0.f;
    float acc = 0.f;
    #pragma unroll
    for (int i = 0; i < 16; ++i) {
        const float2 vA = ((const float2*)(sal + (size_t)(r0 + 2 * i) * WW))[tid];
        const float2 vB = ((const float2*)(sal + (size_t)(r0 + 2 * i + 1) * WW))[tid];
        acc += fminf(a0[i].x * invSn, vA.x * invSal);
        acc += fminf(a1[i].x * invSn, vA.y * invSal);
        acc += fminf(a0[i].y * invSn, vB.x * invSal);
        acc += fminf(a1[i].y * invSn, vB.y * invSal);
    }
    for (int o = 32; o > 0; o >>= 1) acc += __shfl_down(acc, o, 64);
    if ((tid & 63) == 0) part[tid >> 6] = acc;
    __syncthreads();
    if (tid == 0) atomicAdd(&out[n], part[0] + part[1] + part[2] + part[3]);
}

extern "C" void kernel_launch(void* const* d_in, const int* in_sizes, int n_in,
                              void* d_out, int out_size, void* d_ws, size_t ws_size,
                              hipStream_t stream) {
    const float* sal = (const float*)d_in[0];
    const int* ns = (const int*)d_in[1];
    const int* ys = (const int*)d_in[2];
    const int* xs = (const int*)d_in[3];
    const int nfix = in_sizes[1];
    const int batch = out_size;          // 128
    float* out = (float*)d_out;

    // ws layout (float-element offsets)
    float* ws      = (float*)d_ws;
    float* kk_g    = ws;                        // 128
    float* partial = ws + 128;                  // SALB floats (192)
    float* ssum_g  = ws + 320;                  // BATCH
    int*   offs_g  = (int*)(ws + 320 + BATCH);  // batch*32 ints
    int*   sorted  = offs_g + BATCH * 32;       // batch*MAXF ints

    k_prep<<<batch + SALB, 256, 0, stream>>>(sal, ns, ys, xs, kk_g, partial,
                                             ssum_g, offs_g, sorted, out,
                                             nfix, batch);
    k_main<<<dim3(NT2, batch), 256, 0, stream>>>(sal, offs_g, sorted,
                                                 ssum_g, partial, kk_g, out);
}

// Round 8
// 46.648 us; speedup vs baseline: 1.0584x; 1.0584x over previous
//
#include <hip/hip_runtime.h>
#include <math.h>

#define HH 384
#define WW 512
#define RR 60
#define KLEN 121             // 2*RR+1
#define TH 16                // rows per tile in k_main
#define NTILES (HH / TH)     // 24
#define BATCH 128            // harness batch (out_size)
#define MAXF 400             // per-image fixation capacity (mean ~100)
#define SALB 192             // saliency partial blocks: 192*256 float4 = HH*WW

typedef float v2f __attribute__((ext_vector_type(2)));

// ---- kernel 1: blocks [0,batch) = per-image bucket sort + mass;
//                blocks [batch, batch+SALB) = saliency partial sums ----------
__global__ __launch_bounds__(256) void k_prep(
    const float* __restrict__ sal, const int* __restrict__ ns,
    const int* __restrict__ ys, const int* __restrict__ xs,
    float* __restrict__ kk_g, float* __restrict__ partial,
    float* __restrict__ ssum_g, int* __restrict__ offs_g,
    int* __restrict__ sorted, float* __restrict__ out,
    int nfix, int batch)
{
    const int tid = threadIdx.x;

    if (blockIdx.x >= batch) {
        // ---- saliency partial: 256 float4 per block, one plain store -------
        __shared__ float redp[4];
        const int sb = blockIdx.x - batch;
        float4 v = ((const float4*)sal)[sb * 256 + tid];
        float a = (v.x + v.y) + (v.z + v.w);
        for (int o = 32; o > 0; o >>= 1) a += __shfl_down(a, o, 64);
        if ((tid & 63) == 0) redp[tid >> 6] = a;
        __syncthreads();
        if (tid == 0) partial[sb] = redp[0] + redp[1] + redp[2] + redp[3];
        return;
    }

    // ---- per-image block ----
    __shared__ float kk_s[KLEN];
    __shared__ float P_s[KLEN + 1];
    __shared__ int   list[MAXF];
    __shared__ int   cntb[NTILES];
    __shared__ int   off_s[NTILES + 1];
    __shared__ int   cur[NTILES];
    __shared__ int   nloc;
    __shared__ float red2[4];

    const int n = blockIdx.x;

    if (tid < KLEN) {
        float xx = (float)(tid - RR) * (1.0f / 20.0f);
        kk_s[tid] = expf(-0.5f * xx * xx);
    }
    if (tid < NTILES) { cntb[tid] = 0; cur[tid] = 0; }
    if (tid == 0) nloc = 0;
    __syncthreads();
    if (tid == 0) {                    // normalize + prefix (242 float ops)
        float s = 0.f;
        for (int t = 0; t < KLEN; ++t) s += kk_s[t];
        float inv = 1.0f / s, run = 0.f;
        for (int t = 0; t < KLEN; ++t) {
            float v = kk_s[t] * inv;
            kk_s[t] = v; P_s[t] = run; run += v;
        }
        P_s[KLEN] = run;
    }
    __syncthreads();

    // scan all fixations (ns is L2-resident), collect this image's
    float ss = 0.f;
    const int4* ns4 = (const int4*)ns;
    const int nf4 = nfix >> 2;
    for (int i = tid; i < nf4; i += 256) {
        int4 n4 = ns4[i];
        #pragma unroll
        for (int e = 0; e < 4; ++e) {
            if ((&n4.x)[e] == n) {
                const int idx = 4 * i + e;
                const int y = ys[idx], x = xs[idx];
                const int pos = atomicAdd(&nloc, 1);
                if (pos < MAXF) list[pos] = (y << 9) | x;
                atomicAdd(&cntb[y >> 4], 1);
                float cy = P_s[RR + min(RR, HH - 1 - y) + 1] - P_s[RR - min(RR, y)];
                float cx = P_s[RR + min(RR, WW - 1 - x) + 1] - P_s[RR - min(RR, x)];
                ss += cy * cx;
            }
        }
    }
    for (int idx = (nf4 << 2) + tid; idx < nfix; idx += 256) {
        if (ns[idx] == n) {
            const int y = ys[idx], x = xs[idx];
            const int pos = atomicAdd(&nloc, 1);
            if (pos < MAXF) list[pos] = (y << 9) | x;
            atomicAdd(&cntb[y >> 4], 1);
            float cy = P_s[RR + min(RR, HH - 1 - y) + 1] - P_s[RR - min(RR, y)];
            float cx = P_s[RR + min(RR, WW - 1 - x) + 1] - P_s[RR - min(RR, x)];
            ss += cy * cx;
        }
    }
    for (int o = 32; o > 0; o >>= 1) ss += __shfl_down(ss, o, 64);
    if ((tid & 63) == 0) red2[tid >> 6] = ss;
    __syncthreads();                   // atomics + red2 done
    if (tid == 0) {
        ssum_g[n] = red2[0] + red2[1] + red2[2] + red2[3];
        int run = 0;                   // exclusive scan over 24 buckets
        for (int t = 0; t < NTILES; ++t) { off_s[t] = run; run += cntb[t]; }
        off_s[NTILES] = run;
    }
    __syncthreads();
    const int m = min(nloc, MAXF);
    for (int j = tid; j < m; j += 256) {
        const int p = list[j];
        const int key = (p >> 9) >> 4;
        const int pos = atomicAdd(&cur[key], 1);
        sorted[n * MAXF + off_s[key] + pos] = p;
    }
    if (tid <= NTILES) offs_g[n * 32 + tid] = n * MAXF + off_s[tid];
    if (n == 0 && tid < KLEN) kk_g[tid] = kk_s[tid];
    if (tid == 0) out[n] = 0.f;
}

// ---------------- main: register-accumulator Gaussian splat, fused min-sum ----
// Thread t owns adjacent columns 2t,2t+1; rows packed in float2 pairs so the
// splat inner loop is 8x ds_read_b64 + 16 packed FMAs (v_pk_fma_f32).
__global__ __launch_bounds__(256) void k_main(
    const float* __restrict__ sal, const int* __restrict__ offs,
    const int* __restrict__ sorted, const float* __restrict__ ssum,
    const float* __restrict__ partial, const float* __restrict__ kk_g,
    float* __restrict__ out)
{
    __shared__ v2f   kpE[84];    // row-weight pairs starting at even kpy index
    __shared__ v2f   kpO[84];    // pairs starting at odd kpy index
    __shared__ float kkx[128];   // x-kernel: [0..120] = kk, [121..127] = 0
    __shared__ int   fix_s[256];
    __shared__ float part[4];
    __shared__ float redp[4];

    const int n   = blockIdx.y;
    const int t   = blockIdx.x;
    const int r0  = t * TH;
    const int tid = threadIdx.x;

    // kpy[u] = (16 <= u <= 136) ? kk[u-16] : 0
    if (tid < 84) {
        const int u = 2 * tid;
        const float e0 = ((unsigned)(u - 16) <= 120u) ? kk_g[u - 16] : 0.f;
        const float e1 = ((unsigned)(u - 15) <= 120u) ? kk_g[u - 15] : 0.f;
        const float e2 = ((unsigned)(u - 14) <= 120u) ? kk_g[u - 14] : 0.f;
        kpE[tid] = (v2f){e0, e1};
        kpO[tid] = (v2f){e1, e2};
    }
    if (tid < 128) kkx[tid] = (tid < KLEN) ? kk_g[tid] : 0.f;
    float psal = (tid < SALB) ? partial[tid] : 0.f;   // issue early

    v2f a0[8], a1[8];
    #pragma unroll
    for (int i = 0; i < 8; ++i) { a0[i] = 0.f; a1[i] = 0.f; }

    const int b0 = max(0, t - 4);
    const int b1 = min(NTILES - 1, t + 4);
    const int s0 = offs[n * 32 + b0], s1 = offs[n * 32 + b1 + 1];

    const int c0  = 2 * tid;
    const int wlo = (tid >> 6) << 7;      // wave's column strip [wlo, wlo+127]
    const int whi = wlo + 127;

    for (int fb = s0; fb < s1; fb += 256) {
        const int m = min(256, s1 - fb);
        if (fb != s0) __syncthreads();            // protect fix_s overwrite
        if (tid < m) fix_s[tid] = sorted[fb + tid];
        __syncthreads();                          // also covers kpE/kpO/kkx once
        for (int f = 0; f < m; ++f) {
            const int p = fix_s[f];               // broadcast LDS read
            const int y = p >> 9, x = p & 511;
            const int base = r0 - y + 76;         // row-weight base in kpy
            if ((unsigned)(base - 1) >= 136u) continue;   // uniform: y skip
            if (x + RR < wlo || x - RR > whi) continue;   // wave-uniform: x skip
            const int idx0 = c0 - x + RR;
            const float wx0 = kkx[min((unsigned)idx0, 127u)];
            const float wx1 = kkx[min((unsigned)(idx0 + 1), 127u)];
            const v2f* kp = (base & 1) ? kpO : kpE;
            const int kb = base >> 1;
            #pragma unroll
            for (int i = 0; i < 8; ++i) {
                const v2f wy = kp[kb + i];        // rows 2i,2i+1 (b64 broadcast)
                a0[i] += wy * wx0;                // v_pk_fma_f32
                a1[i] += wy * wx1;
            }
        }
    }

    // reduce saliency partials -> invSal
    for (int o = 32; o > 0; o >>= 1) psal += __shfl_down(psal, o, 64);
    if ((tid & 63) == 0) redp[tid >> 6] = psal;
    __syncthreads();
    const float invSal = 1.0f / (redp[0] + redp[1] + redp[2] + redp[3]);

    const float sN    = ssum[n];
    const float invSn = sN > 0.f ? 1.0f / sN : 0.f;
    float acc = 0.f;
    #pragma unroll
    for (int i = 0; i < 8; ++i) {
        const float2 vA = ((const float2*)(sal + (size_t)(r0 + 2 * i) * WW))[tid];
        const float2 vB = ((const float2*)(sal + (size_t)(r0 + 2 * i + 1) * WW))[tid];
        acc += fminf(a0[i].x * invSn, vA.x * invSal);
        acc += fminf(a1[i].x * invSn, vA.y * invSal);
        acc += fminf(a0[i].y * invSn, vB.x * invSal);
        acc += fminf(a1[i].y * invSn, vB.y * invSal);
    }
    for (int o = 32; o > 0; o >>= 1) acc += __shfl_down(acc, o, 64);
    if ((tid & 63) == 0) part[tid >> 6] = acc;
    __syncthreads();
    if (tid == 0) atomicAdd(&out[n], part[0] + part[1] + part[2] + part[3]);
}

extern "C" void kernel_launch(void* const* d_in, const int* in_sizes, int n_in,
                              void* d_out, int out_size, void* d_ws, size_t ws_size,
                              hipStream_t stream) {
    const float* sal = (const float*)d_in[0];
    const int* ns = (const int*)d_in[1];
    const int* ys = (const int*)d_in[2];
    const int* xs = (const int*)d_in[3];
    const int nfix = in_sizes[1];
    const int batch = out_size;          // 128
    float* out = (float*)d_out;

    // ws layout (float-element offsets)
    float* ws      = (float*)d_ws;
    float* kk_g    = ws;                        // 128
    float* partial = ws + 128;                  // SALB floats (192)
    float* ssum_g  = ws + 320;                  // BATCH
    int*   offs_g  = (int*)(ws + 320 + BATCH);  // batch*32 ints
    int*   sorted  = offs_g + BATCH * 32;       // batch*MAXF ints

    k_prep<<<batch + SALB, 256, 0, stream>>>(sal, ns, ys, xs, kk_g, partial,
                                             ssum_g, offs_g, sorted, out,
                                             nfix, batch);
    k_main<<<dim3(NTILES, batch), 256, 0, stream>>>(sal, offs_g, sorted,
                                                    ssum_g, partial, kk_g, out);
}